// Round 3
// baseline (741.244 us; speedup 1.0000x reference)
//
#include <hip/hip_runtime.h>

#define NN 24576
#define DD 32
#define KK 17
#define PP 20

// Bernstein basis of order 16: b[k] = C(16,k) * x^k * (1-x)^(16-k)
__device__ __forceinline__ void bern17(float x, float* b) {
    const float binom[KK] = {1.f, 16.f, 120.f, 560.f, 1820.f, 4368.f, 8008.f, 11440.f,
                             12870.f, 11440.f, 8008.f, 4368.f, 1820.f, 560.f, 120.f, 16.f, 1.f};
    const float y = 1.0f - x;
    b[0] = 1.0f;
#pragma unroll
    for (int k = 1; k < KK; ++k) b[k] = b[k - 1] * x;   // b[k] = x^k
    float yp = 1.0f;
#pragma unroll
    for (int k = KK - 1; k >= 0; --k) {                  // multiply (1-x)^(16-k) * binom
        b[k] = b[k] * yp * binom[k];
        yp *= y;
    }
}

// Precompute var-chain weights: wv[d,p,k,j] = exp(varw[d,p,k,j]) * sc2[j]
//                               wv0[p,k]    = exp(varw0[p,0,k]) * sc2[k]
__global__ void prep_var(const float* __restrict__ varw, const float* __restrict__ varw0,
                         const float* __restrict__ prior_sc,
                         float* __restrict__ wv, float* __restrict__ wv0) {
    const int E1 = (DD - 1) * PP * KK * KK;
    int idx = blockIdx.x * blockDim.x + threadIdx.x;
    if (idx < E1) {
        int j = idx % KK;
        float s = prior_sc[j];
        wv[idx] = expf(varw[idx]) * s * s;
    } else if (idx < E1 + PP * KK) {
        int i = idx - E1;
        int k = i % KK;
        float s = prior_sc[k];
        wv0[i] = expf(varw0[i]) * s * s;
    }
}

// Precompute Bernstein basis for an n-chunk: B[d][k][i] = bern(X[n0+i][d])[k].
// Computed ONCE instead of 40x (20 perms x 2 chains) inside the chain kernel.
__global__ void bern_prep(const float* __restrict__ X, float* __restrict__ B,
                          const int n0, const int chunkN) {
    const int i = blockIdx.x * blockDim.x + threadIdx.x;
    if (i >= chunkN) return;
    const int n = n0 + i;
    float b[KK];
    for (int d = 0; d < DD; ++d) {
        const float x = X[(size_t)n * DD + d];
        bern17(x, b);
#pragma unroll
        for (int k = 0; k < KK; ++k)
            B[((size_t)d * KK + k) * chunkN + i] = b[k];   // lane-coalesced store
    }
}

// Chain kernel, basis from memory: zero bern work, no serial dep chain.
// blockIdx.x encodes (p, chain-type) so all 40 blocks of one n-tile are
// dispatched consecutively -> co-resident blocks on an XCD share a small
// B slice (~3.6 MB) -> L2-resident B re-reads.
__global__ __launch_bounds__(256, 8) void bez_chainB(
    const float* __restrict__ B, const int chunkN, const int n0,
    const float* __restrict__ mw0,      // [PP,KK]
    const float* __restrict__ mW,       // [DD-1,PP,KK,KK]
    const float* __restrict__ vw0,      // [PP,KK] pre-scaled
    const float* __restrict__ vW,       // [DD-1,PP,KK,KK] pre-scaled
    const float* __restrict__ post_prec,// [PP]
    const int* __restrict__ perm,       // [PP,DD]
    float* __restrict__ out)            // [2*NN]
{
    const int bx = blockIdx.x;                 // 0..2*PP-1
    const bool VAR = (bx >= PP);
    const int p = VAR ? (bx - PP) : bx;
    const int i = blockIdx.y * blockDim.x + threadIdx.x;
    const int n = n0 + i;
    const int* __restrict__ pp = perm + p * DD;

    const float* __restrict__ w0 = VAR ? vw0 : mw0;
    const float* __restrict__ W  = VAR ? vW  : mW;

    float f[KK], bn[KK];

    {
        const int pd = pp[0];
        const float* __restrict__ Bd = B + (size_t)pd * KK * chunkN + i;
#pragma unroll
        for (int k = 0; k < KK; ++k) bn[k] = Bd[(size_t)k * chunkN];
        const float* __restrict__ w0p = w0 + p * KK;
        if (VAR) {
#pragma unroll
            for (int k = 0; k < KK; ++k) f[k] = w0p[k] * (bn[k] * bn[k]);
        } else {
#pragma unroll
            for (int k = 0; k < KK; ++k) f[k] = w0p[k] * bn[k];
        }
    }

#pragma unroll 1
    for (int d = 1; d < DD; ++d) {
        const int pd = pp[d];
        // Issue this step's 17 basis loads FIRST; they are consumed only
        // after the 289-FMA block below -> latency fully covered.
        const float* __restrict__ Bd = B + (size_t)pd * KK * chunkN + i;
#pragma unroll
        for (int k = 0; k < KK; ++k) bn[k] = Bd[(size_t)k * chunkN];

        const float* __restrict__ Wd = W + ((size_t)(d - 1) * PP + p) * (KK * KK);

        float fn[KK];
#pragma unroll
        for (int j = 0; j < KK; ++j) fn[j] = f[0] * Wd[j];     // mul, not mov+fma
#pragma unroll
        for (int k = 1; k < KK; ++k) {
            const float fk = f[k];
#pragma unroll
            for (int j = 0; j < KK; ++j)
                fn[j] = fmaf(fk, Wd[k * KK + j], fn[j]);       // uniform -> scalar loads
        }

        if (VAR) {
#pragma unroll
            for (int j = 0; j < KK; ++j) f[j] = fn[j] * (bn[j] * bn[j]);
        } else {
#pragma unroll
            for (int j = 0; j < KK; ++j) f[j] = fn[j] * bn[j];
        }
    }

    float s = 0.0f;
#pragma unroll
    for (int j = 0; j < KK; ++j) s += f[j];
    if (VAR) s /= post_prec[p];

    atomicAdd(&out[(VAR ? NN : 0) + n], s);
}

// ---------- round-2 fallback path (used only if workspace is tiny) ----------
__global__ void transpose_x(const float* __restrict__ X, float* __restrict__ XT) {
    __shared__ float t[32][33];
    const int n0 = blockIdx.x * 32;
    for (int r = threadIdx.y; r < 32; r += 8)
        t[r][threadIdx.x] = X[(n0 + r) * DD + threadIdx.x];
    __syncthreads();
    for (int d = threadIdx.y; d < 32; d += 8)
        XT[d * NN + n0 + threadIdx.x] = t[threadIdx.x][d];
}

__global__ __launch_bounds__(256, 4) void bez_chain2(
    const float* __restrict__ Xb, const int sx_d, const int sx_n,
    const float* __restrict__ mw0, const float* __restrict__ mW,
    const float* __restrict__ vw0, const float* __restrict__ vW,
    const float* __restrict__ post_prec, const int* __restrict__ perm,
    float* __restrict__ out)
{
    const bool VAR = (blockIdx.z != 0);
    const int p = blockIdx.y;
    const int n = blockIdx.x * blockDim.x + threadIdx.x;
    const int* __restrict__ pp = perm + p * DD;
    const float* __restrict__ w0 = (VAR ? vw0 : mw0);
    const float* __restrict__ W  = (VAR ? vW  : mW);

    float f[KK], b[KK];
    {
        const int pd = pp[0];
        const float x = Xb[pd * sx_d + n * sx_n];
        bern17(x, b);
        if (VAR) {
#pragma unroll
            for (int k = 0; k < KK; ++k) b[k] *= b[k];
        }
        const float* __restrict__ w0p = w0 + p * KK;
#pragma unroll
        for (int k = 0; k < KK; ++k) f[k] = w0p[k] * b[k];
    }
    for (int d = 1; d < DD; ++d) {
        const int pd = pp[d];
        const float x = Xb[pd * sx_d + n * sx_n];
        bern17(x, b);
        if (VAR) {
#pragma unroll
            for (int k = 0; k < KK; ++k) b[k] *= b[k];
        }
        const float* __restrict__ Wd = W + ((size_t)(d - 1) * PP + p) * (KK * KK);
        float fn[KK];
#pragma unroll
        for (int j = 0; j < KK; ++j) fn[j] = 0.0f;
#pragma unroll
        for (int k = 0; k < KK; ++k) {
            const float fk = f[k];
#pragma unroll
            for (int j = 0; j < KK; ++j)
                fn[j] = fmaf(fk, Wd[k * KK + j], fn[j]);
        }
#pragma unroll
        for (int j = 0; j < KK; ++j) f[j] = fn[j] * b[j];
    }
    float s = 0.0f;
#pragma unroll
    for (int j = 0; j < KK; ++j) s += f[j];
    if (VAR) s /= post_prec[p];
    atomicAdd(&out[(VAR ? NN : 0) + n], s);
}
// ---------------------------------------------------------------------------

extern "C" void kernel_launch(void* const* d_in, const int* in_sizes, int n_in,
                              void* d_out, int out_size, void* d_ws, size_t ws_size,
                              hipStream_t stream) {
    const float* X    = (const float*)d_in[0];
    const float* mw0  = (const float*)d_in[1];
    const float* mw   = (const float*)d_in[2];
    const float* vw0  = (const float*)d_in[3];
    const float* vw   = (const float*)d_in[4];
    const float* psc  = (const float*)d_in[5];
    const float* ppr  = (const float*)d_in[6];
    const int*   perm = (const int*)d_in[7];
    float* out = (float*)d_out;

    const size_t wv_elems  = (size_t)(DD - 1) * PP * KK * KK;
    const size_t wv0_elems = (size_t)PP * KK;

    float* wv  = (float*)d_ws;
    float* wv0 = wv + wv_elems;
    float* Bws = wv0 + wv0_elems;

    hipMemsetAsync(d_out, 0, (size_t)out_size * sizeof(float), stream);

    const int E = (DD - 1) * PP * KK * KK + PP * KK;
    prep_var<<<dim3((E + 255) / 256), dim3(256), 0, stream>>>(vw, vw0, psc, wv, wv0);

    // Pick the largest n-chunk whose basis table fits the workspace.
    int nchunks = 0;
    for (int c = 1; c <= 16; c *= 2) {
        const size_t bElems = (size_t)DD * KK * (NN / c);
        if ((wv_elems + wv0_elems + bElems) * sizeof(float) <= ws_size) { nchunks = c; break; }
    }

    if (nchunks > 0) {
        const int chunkN = NN / nchunks;
        for (int c = 0; c < nchunks; ++c) {
            const int n0 = c * chunkN;
            bern_prep<<<dim3((chunkN + 255) / 256), dim3(256), 0, stream>>>(X, Bws, n0, chunkN);
            dim3 grid(2 * PP, chunkN / 256), blk(256);
            bez_chainB<<<grid, blk, 0, stream>>>(Bws, chunkN, n0, mw0, mw, wv0, wv,
                                                 ppr, perm, out);
        }
    } else {
        // Tiny workspace: round-2 path.
        const size_t xt_elems = (size_t)DD * NN;
        const bool use_xt = ((wv_elems + wv0_elems + xt_elems) * sizeof(float) <= ws_size);
        const float* Xb = X;
        int sx_d = 1, sx_n = DD;
        if (use_xt) {
            float* XT = Bws;
            transpose_x<<<dim3(NN / 32), dim3(32, 8), 0, stream>>>(X, XT);
            Xb = XT; sx_d = NN; sx_n = 1;
        }
        dim3 grid(NN / 256, PP, 2), blk(256);
        bez_chain2<<<grid, blk, 0, stream>>>(Xb, sx_d, sx_n, mw0, mw, wv0, wv, ppr, perm, out);
    }
}